// Round 9
// baseline (261.407 us; speedup 1.0000x reference)
//
#include <hip/hip_runtime.h>
#include <hip/hip_fp16.h>
#include <math.h>

// ---------------------------------------------------------------------------
// GNN pool: 2x GCNConv(elu) + MLP(128) + Linear(15) + softmax
// N=100000, E=3200000, IN=3, HID=64, MLP_HID=128, K=15, fp32 in/out.
//
// Round-23 pipeline (5 dispatches incl. memset):
//   memset cursor -> scatter512 (+prep) -> csr_sort512 (compact stage,
//   uint4 PADDED writeback) -> agg3 -> aggmlp (FUSED agg64+h1: per-block
//   aggregate 64 nodes into LDS, then MFMA MLP in place)
//
// r22 measurements: (a) all hidden kernels < 43us each (none topped the
// 44us harness fills); (b) dispatch boundary ~5us (+3 splits = +17us);
// (c) hidden mass is distributed + ~25us launch gaps.
// r23: fuse h1 into agg64 (the only legal fusion: h1's 64-node tile = the
// a2h rows its own block produces). a2h lives in LDS aliased over ms
// (28.7KB/block, 5 blocks/CU, 20 waves/CU — gather is miss-slot bound,
// not wave-bound per r15-r17, so phase 1 should hold ~52us). Saves: 1
// boundary (5us) + h1 standalone time hidden under miss slack (8-10us) +
// a2h 25MB round trip (3us). Sort writeback -> aligned uint4 stores.
// Predict: total 235.5 -> 218-228; aggmlp 56-64us, WRITE ~6MB, FETCH
// ~160MB; absmax unchanged. Falsifier: aggmlp >= 68 => occupancy-
// sensitive gather -> revert fusion.
// ---------------------------------------------------------------------------

#define SPAN 128          // nodes per bucket
#define CAPP 6400         // global bucket stride incl. pads
#define CAPC 4608         // compact LDS capacity (edges only)
#define CH   8192         // edges per scatter chunk (391 chunks)
#define EPT  16           // edges per thread in scatter (512 threads)
#define H2P  88           // h2s row pad (halfs)
#define MSP2 136          // ms row pad (halfs)
#define A2P  72           // a2s row pad (halfs): 144B rows, 2-way banks max

typedef _Float16 v8hf __attribute__((ext_vector_type(8)));
typedef float    v4f  __attribute__((ext_vector_type(4)));

__device__ __forceinline__ float elu(float v) { return v > 0.f ? v : expm1f(v); }

// ---- scatter (512 thr): edges -> buckets by dst>>7; last block = prep ----
__global__ __launch_bounds__(512) void scatter_kernel(const int* __restrict__ src,
    const int* __restrict__ dst, int* __restrict__ cursor, unsigned* __restrict__ colb,
    const float* __restrict__ W2, const float* __restrict__ Wm1,
    const float* __restrict__ Wm2, __half* __restrict__ W2t,
    __half* __restrict__ Wm1t, __half* __restrict__ Wm2p,
    __half* __restrict__ s1h, __half* __restrict__ sxh,
    int E, int NBK, int nChunks, int N) {
    int tid = threadIdx.x;
    if ((int)blockIdx.x == nChunks) {   // ---- prep block ----
        for (int i = tid; i < 64 * 64; i += 512) {
            int f = i >> 6, k = i & 63;
            W2t[f * 64 + k] = __float2half(W2[k * 64 + f]);
        }
        for (int i = tid; i < 128 * 64; i += 512) {
            int j = i >> 6, f = i & 63;
            Wm1t[j * 64 + f] = __float2half(Wm1[f * 128 + j]);
        }
        for (int i = tid; i < 4 * 64 * 8; i += 512) {
            int j = i & 7, l = (i >> 3) & 63, t = i >> 9;
            int k = t * 32 + (l >> 4) * 8 + j;
            int c = l & 15;
            Wm2p[i] = (c < 15) ? __float2half(Wm2[k * 15 + c]) : __half(0.f);
        }
        // zero-row N: gather target for pad slots
        if (tid < 32) {
            ((uint2*)(s1h + (size_t)N * 64))[tid & 15] = uint2{0u, 0u};  // 128B
            if (tid == 16) *((uint2*)(sxh + (size_t)N * 4)) = uint2{0u, 0u}; // 8B
        }
        return;
    }
    __shared__ int hist[1024];
    __shared__ unsigned gb[1024];
    int chunk = blockIdx.x;
    for (int i = tid; i < NBK; i += 512) hist[i] = 0;
    __syncthreads();
    int base = chunk * CH;
    int cnt = min(CH, E - base);
    unsigned br[EPT], dt[EPT];
#pragma unroll
    for (int j = 0; j < EPT; ++j) {
        int idx = j * 512 + tid;
        br[j] = 0xFFFFFFFFu;
        if (idx < cnt) {
            int e = base + idx;
            int s = src[e], d = dst[e];
            int b = d >> 7;
            int r = atomicAdd(&hist[b], 1);
            br[j] = ((unsigned)b << 13) | (unsigned)r;   // b<1024(10b), r<8192(13b)
            dt[j] = ((unsigned)(d & 127) << 17) | (unsigned)s;
        }
    }
    __syncthreads();
    for (int b = tid; b < NBK; b += 512) {
        int c = hist[b];
        gb[b] = (unsigned)(b * CAPP) + (c ? (unsigned)atomicAdd(&cursor[b], c) : 0u);
    }
    __syncthreads();
#pragma unroll
    for (int j = 0; j < EPT; ++j) {
        if (br[j] != 0xFFFFFFFFu) {
            int b = br[j] >> 13;
            int r = br[j] & 8191;
            unsigned pos = gb[b] + (unsigned)r;
            if (pos < (unsigned)(b + 1) * CAPP) colb[pos] = dt[j];
        }
    }
}

// ---- per-bucket counting sort: COMPACT LDS staging, uint4 PADDED writeback ----
// Global node layout: [start, start+c) edges, [start+c] self, pads -> N up
// to start+pk, pk = round16(c+1). rp2 = (start, start+c+1) REAL end.
__global__ __launch_bounds__(512) void csr_sort_kernel(unsigned* __restrict__ colb,
    const int* __restrict__ cursor, const float* __restrict__ x,
    uint2* __restrict__ rp2, float* __restrict__ dis, __half* __restrict__ sxh,
    int N) {
    __shared__ __align__(16) unsigned ebuf[CAPC];
    __shared__ __align__(16) int sbuf[CAPC];
    __shared__ int cnt[SPAN], offC[SPAN], offP[SPAN], fill[SPAN];
    int b = blockIdx.x, tid = threadIdx.x;
    int n = min(cursor[b], CAPC);
    size_t base = (size_t)b * CAPP;
    if (tid < SPAN) cnt[tid] = 0;
    int n4 = n >> 2;
    for (int k = tid; k < n4; k += 512)
        *(uint4*)(ebuf + 4 * k) = *(const uint4*)(colb + base + 4 * k);
    for (int i = (n4 << 2) + tid; i < n; i += 512) ebuf[i] = colb[base + i];
    __syncthreads();
    for (int i = tid; i < n; i += 512) atomicAdd(&cnt[(ebuf[i] >> 17) & 127], 1);
    __syncthreads();
    // single-wave dual scan: compact (sbuf) + padded (global) offsets
    if (tid < 64) {
        int n0 = b * SPAN + tid, n1 = n0 + 64;
        int c0 = cnt[tid], c1 = cnt[tid + 64];
        int sc0 = (n0 < N) ? c0 : 0;
        int sc1 = (n1 < N) ? c1 : 0;
        int sp0 = (n0 < N) ? ((c0 + 16) & ~15) : 0;
        int sp1 = (n1 < N) ? ((c1 + 16) & ~15) : 0;
        int a0 = sc0, a1 = sc1, p0 = sp0, p1 = sp1;
#pragma unroll
        for (int off = 1; off < 64; off <<= 1) {
            int t0 = __shfl_up(a0, off), t1 = __shfl_up(a1, off);
            int u0 = __shfl_up(p0, off), u1 = __shfl_up(p1, off);
            if (tid >= off) { a0 += t0; a1 += t1; p0 += u0; p1 += u1; }
        }
        int totC = __shfl(a0, 63), totP = __shfl(p0, 63);
        offC[tid]      = a0 - sc0;              // exclusive compact
        offC[tid + 64] = totC + a1 - sc1;
        offP[tid]      = p0 - sp0;              // exclusive padded
        offP[tid + 64] = totP + p1 - sp1;
    }
    __syncthreads();
    if (tid < SPAN) {
        fill[tid] = offC[tid];
        int node = b * SPAN + tid;
        if (node < N) {
            int c = cnt[tid];
            uint2 rp;
            rp.x = (unsigned)(base + offP[tid]);
            rp.y = rp.x + (unsigned)c + 1u;     // REAL end (self incl)
            rp2[node] = rp;
            float r = rsqrtf((float)(c + 1));
            dis[node] = r;
            __half2 h0 = __floats2half2_rn(r * x[node * 3 + 0], r * x[node * 3 + 1]);
            __half2 h1 = __floats2half2_rn(r * x[node * 3 + 2], 0.f);
            uint2 w; w.x = *(unsigned*)&h0; w.y = *(unsigned*)&h1;
            *(uint2*)(sxh + (size_t)node * 4) = w;
        }
    }
    __syncthreads();
    for (int i = tid; i < n; i += 512) {
        unsigned e = ebuf[i];
        int pos = atomicAdd(&fill[(e >> 17) & 127], 1);
        sbuf[pos] = (int)(e & 0x1FFFF);
    }
    __syncthreads();
    // padded per-node writeback: 16 half-waves x 8 nodes; aligned uint4 stores
    // (gp is a multiple of 16 elements: offP entries are round16 prefixes)
    int hw = tid >> 5, hl = tid & 31;
    for (int nd = hw; nd < SPAN; nd += 16) {
        int node = b * SPAN + nd;
        if (node >= N) continue;
        int c = cnt[nd], oc = offC[nd];
        unsigned gp = (unsigned)(base + offP[nd]);
        int pk4 = ((c + 16) & ~15) >> 2;
        for (int j4 = hl; j4 < pk4; j4 += 32) {
            int j = j4 << 2;
            uint4 v;
            v.x = (j     < c) ? (unsigned)sbuf[oc + j]     : ((j     == c) ? (unsigned)node : (unsigned)N);
            v.y = (j + 1 < c) ? (unsigned)sbuf[oc + j + 1] : ((j + 1 == c) ? (unsigned)node : (unsigned)N);
            v.z = (j + 2 < c) ? (unsigned)sbuf[oc + j + 2] : ((j + 2 == c) ? (unsigned)node : (unsigned)N);
            v.w = (j + 3 < c) ? (unsigned)sbuf[oc + j + 3] : ((j + 3 == c) ? (unsigned)node : (unsigned)N);
            *(uint4*)(colb + gp + j) = v;
        }
    }
}

// ---- layer 1: 2 nodes/wave (32 lanes each), 8B gathers; REAL slots only ----
__global__ void agg3_kernel(const __half* __restrict__ sxh, const uint2* __restrict__ rp2,
                            const unsigned* __restrict__ colb, const float* __restrict__ dis,
                            const float* __restrict__ W1, const float* __restrict__ b1,
                            __half* __restrict__ s1h, int N) {
    int wave = (blockIdx.x * blockDim.x + threadIdx.x) >> 6;
    int lane = threadIdx.x & 63;
    int hl = lane & 31;
    int d = wave * 2 + (lane >> 5);
    bool act = d < N;
    int start = 0, end = 0;
    if (act) { uint2 rp = rp2[d]; start = (int)rp.x; end = (int)rp.y; }
    float a0 = 0.f, a1 = 0.f, a2v = 0.f;
    for (int i = start + hl; i < end; i += 32) {   // self included, no pads
        uint2 rq = *(const uint2*)(sxh + (size_t)colb[i] * 4);
        float2 u0 = __half22float2(*(__half2*)&rq.x);
        float2 u1 = __half22float2(*(__half2*)&rq.y);
        a0 += u0.x; a1 += u0.y; a2v += u1.x;
    }
#pragma unroll
    for (int off = 16; off; off >>= 1) {
        a0  += __shfl_xor(a0, off);
        a1  += __shfl_xor(a1, off);
        a2v += __shfl_xor(a2v, off);
    }
    if (act) {
        float r = dis[d];
        float v0 = r * (a0 * W1[hl]      + a1 * W1[64 + hl]      + a2v * W1[128 + hl])      + b1[hl];
        float v1 = r * (a0 * W1[32 + hl] + a1 * W1[96 + hl]      + a2v * W1[160 + hl])      + b1[32 + hl];
        s1h[(size_t)d * 64 + hl]      = __float2half(r * elu(v0));
        s1h[(size_t)d * 64 + 32 + hl] = __float2half(r * elu(v1));
    }
}

// ---- FUSED layer-2 aggregate + MLP + softmax ----
// Block = 256 thr / 4 waves / 64 nodes. Phase 1: wave w aggregates nodes
// base+w*16..+15 (8 lanes/slot, 16B/lane) into LDS a2s (aliased over ms).
// Phase 2: h1's 3 MFMA stages reading a2s instead of global a2h.
__global__ __launch_bounds__(256) void aggmlp_kernel(const __half* __restrict__ s1h,
    const uint2* __restrict__ rp2, const unsigned* __restrict__ colb,
    const float* __restrict__ dis,
    const __half* __restrict__ W2t, const float* __restrict__ b2g,
    const __half* __restrict__ Wm1t, const float* __restrict__ bm1g,
    const __half* __restrict__ Wm2p, const float* __restrict__ bm2g,
    float* __restrict__ out, int N) {
    __shared__ __align__(16) __half h2s[64 * H2P];    // 11.3 KB
    __shared__ __align__(16) __half msb[64 * MSP2];   // 17.4 KB (ms; a2s aliased)
    __half* a2s = msb;                                // a2s: 64*A2P = 4608 halfs, dead before ms written
    int tid = threadIdx.x;
    int wave = tid >> 6, lane = tid & 63;
    int base = blockIdx.x * 64;
    int g = lane >> 3;          // edge slot (0..7)
    int f = lane & 7;           // feature octet

    // ---- phase 1: aggregate 16 nodes per wave ----
    for (int k = 0; k < 16; ++k) {
        int local = wave * 16 + k;
        int d = base + local;
        float acc0 = 0.f, acc1 = 0.f, acc2 = 0.f, acc3 = 0.f;
        float acc4 = 0.f, acc5 = 0.f, acc6 = 0.f, acc7 = 0.f;
        float r = 0.f;
        if (d < N) {
            uint2 rp = rp2[d];
            r = dis[d];
            int start = (int)rp.x;
            int len = (int)(rp.y - rp.x);
            int pend = start + ((len + 15) & ~15);
            for (int i = start; i < pend; i += 16) {
                int ca = (int)colb[i + g];
                int cb = (int)colb[i + 8 + g];
                uint4 A = *(const uint4*)(s1h + (size_t)ca * 64 + f * 8);
                uint4 B = *(const uint4*)(s1h + (size_t)cb * 64 + f * 8);
                __half2 p0 = __hadd2(*(__half2*)&A.x, *(__half2*)&B.x);
                __half2 p1 = __hadd2(*(__half2*)&A.y, *(__half2*)&B.y);
                __half2 p2 = __hadd2(*(__half2*)&A.z, *(__half2*)&B.z);
                __half2 p3 = __hadd2(*(__half2*)&A.w, *(__half2*)&B.w);
                float2 q0 = __half22float2(p0);
                float2 q1 = __half22float2(p1);
                float2 q2 = __half22float2(p2);
                float2 q3 = __half22float2(p3);
                acc0 += q0.x; acc1 += q0.y; acc2 += q1.x; acc3 += q1.y;
                acc4 += q2.x; acc5 += q2.y; acc6 += q3.x; acc7 += q3.y;
            }
        }
#pragma unroll
        for (int off = 8; off <= 32; off <<= 1) {
            acc0 += __shfl_xor(acc0, off);
            acc1 += __shfl_xor(acc1, off);
            acc2 += __shfl_xor(acc2, off);
            acc3 += __shfl_xor(acc3, off);
            acc4 += __shfl_xor(acc4, off);
            acc5 += __shfl_xor(acc5, off);
            acc6 += __shfl_xor(acc6, off);
            acc7 += __shfl_xor(acc7, off);
        }
        if (g == 0) {
            __half2 o0 = __floats2half2_rn(r * acc0, r * acc1);
            __half2 o1 = __floats2half2_rn(r * acc2, r * acc3);
            __half2 o2 = __floats2half2_rn(r * acc4, r * acc5);
            __half2 o3 = __floats2half2_rn(r * acc6, r * acc7);
            uint4 w;
            w.x = *(unsigned*)&o0; w.y = *(unsigned*)&o1;
            w.z = *(unsigned*)&o2; w.w = *(unsigned*)&o3;
            *(uint4*)(a2s + local * A2P + f * 8) = w;   // 16B aligned (144B rows)
        }
    }
    __syncthreads();

    int q = lane >> 4, l16 = lane & 15;
    v8hf wc[4];
#pragma unroll
    for (int t = 0; t < 4; ++t)
        wc[t] = *(const v8hf*)(Wm2p + ((size_t)(t * 64 + lane)) * 8);
    float bbc = (l16 < 15) ? bm2g[l16] : 0.f;

    // ---- stage A: D[m=node16][n=f] = a2s @ W2 ----
    {
        int arow = (wave * 16 + l16) * A2P;
        v8hf af0 = *(const v8hf*)(a2s + arow + q * 8);
        v8hf af1 = *(const v8hf*)(a2s + arow + 32 + q * 8);
#pragma unroll
        for (int fb = 0; fb < 4; ++fb) {
            float bb = b2g[fb * 16 + l16];
            v4f acc = {bb, bb, bb, bb};
            v8hf b0 = *(const v8hf*)(W2t + (fb * 16 + l16) * 64 + q * 8);
            v8hf b1 = *(const v8hf*)(W2t + (fb * 16 + l16) * 64 + 32 + q * 8);
            acc = __builtin_amdgcn_mfma_f32_16x16x32_f16(af0, b0, acc, 0, 0, 0);
            acc = __builtin_amdgcn_mfma_f32_16x16x32_f16(af1, b1, acc, 0, 0, 0);
#pragma unroll
            for (int r = 0; r < 4; ++r)
                h2s[(wave * 16 + q * 4 + r) * H2P + fb * 16 + l16] =
                    __float2half(elu(acc[r]));
        }
    }
    __syncthreads();
    // ---- stage B: D[m=node16][n=j] = h2 @ Wm1 (ms overwrites dead a2s) ----
    {
        int arow = (wave * 16 + l16) * H2P;
        v8hf af0 = *(const v8hf*)(h2s + arow + q * 8);
        v8hf af1 = *(const v8hf*)(h2s + arow + 32 + q * 8);
#pragma unroll
        for (int jb = 0; jb < 8; ++jb) {
            float bb = bm1g[jb * 16 + l16];
            v4f acc = {bb, bb, bb, bb};
            v8hf b0 = *(const v8hf*)(Wm1t + (jb * 16 + l16) * 64 + q * 8);
            v8hf b1 = *(const v8hf*)(Wm1t + (jb * 16 + l16) * 64 + 32 + q * 8);
            acc = __builtin_amdgcn_mfma_f32_16x16x32_f16(af0, b0, acc, 0, 0, 0);
            acc = __builtin_amdgcn_mfma_f32_16x16x32_f16(af1, b1, acc, 0, 0, 0);
#pragma unroll
            for (int r = 0; r < 4; ++r)
                msb[(wave * 16 + q * 4 + r) * MSP2 + jb * 16 + l16] =
                    __float2half(elu(acc[r]));
        }
    }
    __syncthreads();
    // ---- stage C: D[m=node16][n=class16] = ms @ Wm2 (K=128), shfl softmax ----
    {
        int arow = (wave * 16 + l16) * MSP2;
        v4f accC = {bbc, bbc, bbc, bbc};
#pragma unroll
        for (int t = 0; t < 4; ++t) {
            v8hf a = *(const v8hf*)(msb + arow + t * 32 + q * 8);
            accC = __builtin_amdgcn_mfma_f32_16x16x32_f16(a, wc[t], accC, 0, 0, 0);
        }
#pragma unroll
        for (int r = 0; r < 4; ++r) {
            float lg = (l16 < 15) ? accC[r] : -1e30f;
            float mx = lg;
            mx = fmaxf(mx, __shfl_xor(mx, 1));
            mx = fmaxf(mx, __shfl_xor(mx, 2));
            mx = fmaxf(mx, __shfl_xor(mx, 4));
            mx = fmaxf(mx, __shfl_xor(mx, 8));
            float ex = (l16 < 15) ? __expf(lg - mx) : 0.f;
            float sden = ex;
            sden += __shfl_xor(sden, 1);
            sden += __shfl_xor(sden, 2);
            sden += __shfl_xor(sden, 4);
            sden += __shfl_xor(sden, 8);
            int node = base + wave * 16 + q * 4 + r;
            if (l16 < 15 && node < N)
                out[(size_t)node * 15 + l16] = ex / sden;
        }
    }
}

extern "C" void kernel_launch(void* const* d_in, const int* in_sizes, int n_in,
                              void* d_out, int out_size, void* d_ws, size_t ws_size,
                              hipStream_t stream) {
    const float* x   = (const float*)d_in[0];
    const int*   ei  = (const int*)d_in[1];
    const float* W1  = (const float*)d_in[2];
    const float* b1  = (const float*)d_in[3];
    const float* W2  = (const float*)d_in[4];
    const float* b2  = (const float*)d_in[5];
    const float* Wm1 = (const float*)d_in[6];
    const float* bm1 = (const float*)d_in[7];
    const float* Wm2 = (const float*)d_in[8];
    const float* bm2 = (const float*)d_in[9];
    float* out = (float*)d_out;

    int N = in_sizes[0] / 3;
    int E = in_sizes[1] / 2;
    const int* src = ei;
    const int* dst = ei + E;
    int NBK = (N + SPAN - 1) / SPAN;   // 782

    uintptr_t p = (uintptr_t)d_ws;
    auto carve = [&](size_t bytes) -> void* {
        p = (p + 255) & ~(uintptr_t)255;
        void* r = (void*)p;
        p += bytes;
        return r;
    };
    unsigned* colb    = (unsigned*)carve((size_t)NBK * CAPP * 4 + 256);
    __half*   s1h     = (__half*)carve((size_t)(N + 1) * 64 * 2);  // +zero row
    int*      cursor  = (int*)carve((size_t)NBK * 4);
    uint2*    rp2     = (uint2*)carve((size_t)N * 8);
    float*    dis     = (float*)carve((size_t)N * 4);
    __half*   sxh     = (__half*)carve((size_t)(N + 1) * 8);       // +zero row
    __half*   W2t     = (__half*)carve(64 * 64 * 2);
    __half*   Wm1t    = (__half*)carve(128 * 64 * 2);
    __half*   Wm2p    = (__half*)carve(4 * 64 * 8 * 2);

    int nChunks = (E + CH - 1) / CH;          // 391
    int aggBlocks = (N + 7) / 8;              // agg3: 2 nodes/wave, 4 waves/block
    int nTiles = (N + 63) / 64;               // aggmlp: 64-node tiles

    hipMemsetAsync(cursor, 0, (size_t)NBK * 4, stream);
    scatter_kernel<<<nChunks + 1, 512, 0, stream>>>(src, dst, cursor, colb,
        W2, Wm1, Wm2, W2t, Wm1t, Wm2p, s1h, sxh, E, NBK, nChunks, N);
    csr_sort_kernel<<<NBK, 512, 0, stream>>>(colb, cursor, x, rp2, dis, sxh, N);
    agg3_kernel<<<aggBlocks, 256, 0, stream>>>(sxh, rp2, colb, dis, W1, b1, s1h, N);
    aggmlp_kernel<<<nTiles, 256, 0, stream>>>(s1h, rp2, colb, dis,
        W2t, b2, Wm1t, bm1, Wm2p, bm2, out, N);
}

// Round 10
// 233.386 us; speedup vs baseline: 1.1201x; 1.1201x over previous
//
#include <hip/hip_runtime.h>
#include <hip/hip_fp16.h>
#include <math.h>

// ---------------------------------------------------------------------------
// GNN pool: 2x GCNConv(elu) + MLP(128) + Linear(15) + softmax
// N=100000, E=3200000, IN=3, HID=64, MLP_HID=128, K=15, fp32 in/out.
//
// Round-24 pipeline (6 dispatches incl. memset):
//   memset cursor -> scatter512 (+prep) -> csr_sort512 (compact stage,
//   uint4 PADDED writeback) -> agg3 -> agg64 (1 node/wave, maskless)
//   -> h1 (all-MFMA)
//
// r23 post-mortem: fusing agg64+h1 collapsed the grid 100K->6.3K waves;
// the gather is TLP-FED (per-CU miss slots filled by wave count, r15-r17)
// so fusion cost 2x despite byte savings. RULE: never trade wave count
// for locality on this gather. r24 restores the 6-dispatch pipeline =
// r21 composition + uint4 aligned writeback in sort (unmeasured micro).
// Predict: total 229-235; agg64 ~52.4 / FETCH ~159.7MB / VALU ~43%.
// If >=234: remaining mass is ~25us of dispatch boundaries (measured r22)
// -> cooperative mega-kernel or plateau.
// ---------------------------------------------------------------------------

#define SPAN 128          // nodes per bucket
#define CAPP 6400         // global bucket stride incl. pads
#define CAPC 4608         // compact LDS capacity (edges only)
#define CH   8192         // edges per scatter chunk (391 chunks)
#define EPT  16           // edges per thread in scatter (512 threads)
#define H2P  88           // h2s row pad (halfs)
#define MSP2 136          // ms row pad (halfs)

typedef _Float16 v8hf __attribute__((ext_vector_type(8)));
typedef float    v4f  __attribute__((ext_vector_type(4)));

__device__ __forceinline__ float elu(float v) { return v > 0.f ? v : expm1f(v); }

// ---- scatter (512 thr): edges -> buckets by dst>>7; last block = prep ----
__global__ __launch_bounds__(512) void scatter_kernel(const int* __restrict__ src,
    const int* __restrict__ dst, int* __restrict__ cursor, unsigned* __restrict__ colb,
    const float* __restrict__ W2, const float* __restrict__ Wm1,
    const float* __restrict__ Wm2, __half* __restrict__ W2t,
    __half* __restrict__ Wm1t, __half* __restrict__ Wm2p,
    __half* __restrict__ s1h, __half* __restrict__ sxh,
    int E, int NBK, int nChunks, int N) {
    int tid = threadIdx.x;
    if ((int)blockIdx.x == nChunks) {   // ---- prep block ----
        for (int i = tid; i < 64 * 64; i += 512) {
            int f = i >> 6, k = i & 63;
            W2t[f * 64 + k] = __float2half(W2[k * 64 + f]);
        }
        for (int i = tid; i < 128 * 64; i += 512) {
            int j = i >> 6, f = i & 63;
            Wm1t[j * 64 + f] = __float2half(Wm1[f * 128 + j]);
        }
        for (int i = tid; i < 4 * 64 * 8; i += 512) {
            int j = i & 7, l = (i >> 3) & 63, t = i >> 9;
            int k = t * 32 + (l >> 4) * 8 + j;
            int c = l & 15;
            Wm2p[i] = (c < 15) ? __float2half(Wm2[k * 15 + c]) : __half(0.f);
        }
        // zero-row N: gather target for pad slots
        if (tid < 32) {
            ((uint2*)(s1h + (size_t)N * 64))[tid & 15] = uint2{0u, 0u};  // 128B
            if (tid == 16) *((uint2*)(sxh + (size_t)N * 4)) = uint2{0u, 0u}; // 8B
        }
        return;
    }
    __shared__ int hist[1024];
    __shared__ unsigned gb[1024];
    int chunk = blockIdx.x;
    for (int i = tid; i < NBK; i += 512) hist[i] = 0;
    __syncthreads();
    int base = chunk * CH;
    int cnt = min(CH, E - base);
    unsigned br[EPT], dt[EPT];
#pragma unroll
    for (int j = 0; j < EPT; ++j) {
        int idx = j * 512 + tid;
        br[j] = 0xFFFFFFFFu;
        if (idx < cnt) {
            int e = base + idx;
            int s = src[e], d = dst[e];
            int b = d >> 7;
            int r = atomicAdd(&hist[b], 1);
            br[j] = ((unsigned)b << 13) | (unsigned)r;   // b<1024(10b), r<8192(13b)
            dt[j] = ((unsigned)(d & 127) << 17) | (unsigned)s;
        }
    }
    __syncthreads();
    for (int b = tid; b < NBK; b += 512) {
        int c = hist[b];
        gb[b] = (unsigned)(b * CAPP) + (c ? (unsigned)atomicAdd(&cursor[b], c) : 0u);
    }
    __syncthreads();
#pragma unroll
    for (int j = 0; j < EPT; ++j) {
        if (br[j] != 0xFFFFFFFFu) {
            int b = br[j] >> 13;
            int r = br[j] & 8191;
            unsigned pos = gb[b] + (unsigned)r;
            if (pos < (unsigned)(b + 1) * CAPP) colb[pos] = dt[j];
        }
    }
}

// ---- per-bucket counting sort: COMPACT LDS staging, uint4 PADDED writeback ----
// Global node layout: [start, start+c) edges, [start+c] self, pads -> N up
// to start+pk, pk = round16(c+1). rp2 = (start, start+c+1) REAL end.
__global__ __launch_bounds__(512) void csr_sort_kernel(unsigned* __restrict__ colb,
    const int* __restrict__ cursor, const float* __restrict__ x,
    uint2* __restrict__ rp2, float* __restrict__ dis, __half* __restrict__ sxh,
    int N) {
    __shared__ __align__(16) unsigned ebuf[CAPC];
    __shared__ __align__(16) int sbuf[CAPC];
    __shared__ int cnt[SPAN], offC[SPAN], offP[SPAN], fill[SPAN];
    int b = blockIdx.x, tid = threadIdx.x;
    int n = min(cursor[b], CAPC);
    size_t base = (size_t)b * CAPP;
    if (tid < SPAN) cnt[tid] = 0;
    int n4 = n >> 2;
    for (int k = tid; k < n4; k += 512)
        *(uint4*)(ebuf + 4 * k) = *(const uint4*)(colb + base + 4 * k);
    for (int i = (n4 << 2) + tid; i < n; i += 512) ebuf[i] = colb[base + i];
    __syncthreads();
    for (int i = tid; i < n; i += 512) atomicAdd(&cnt[(ebuf[i] >> 17) & 127], 1);
    __syncthreads();
    // single-wave dual scan: compact (sbuf) + padded (global) offsets
    if (tid < 64) {
        int n0 = b * SPAN + tid, n1 = n0 + 64;
        int c0 = cnt[tid], c1 = cnt[tid + 64];
        int sc0 = (n0 < N) ? c0 : 0;
        int sc1 = (n1 < N) ? c1 : 0;
        int sp0 = (n0 < N) ? ((c0 + 16) & ~15) : 0;
        int sp1 = (n1 < N) ? ((c1 + 16) & ~15) : 0;
        int a0 = sc0, a1 = sc1, p0 = sp0, p1 = sp1;
#pragma unroll
        for (int off = 1; off < 64; off <<= 1) {
            int t0 = __shfl_up(a0, off), t1 = __shfl_up(a1, off);
            int u0 = __shfl_up(p0, off), u1 = __shfl_up(p1, off);
            if (tid >= off) { a0 += t0; a1 += t1; p0 += u0; p1 += u1; }
        }
        int totC = __shfl(a0, 63), totP = __shfl(p0, 63);
        offC[tid]      = a0 - sc0;              // exclusive compact
        offC[tid + 64] = totC + a1 - sc1;
        offP[tid]      = p0 - sp0;              // exclusive padded
        offP[tid + 64] = totP + p1 - sp1;
    }
    __syncthreads();
    if (tid < SPAN) {
        fill[tid] = offC[tid];
        int node = b * SPAN + tid;
        if (node < N) {
            int c = cnt[tid];
            uint2 rp;
            rp.x = (unsigned)(base + offP[tid]);
            rp.y = rp.x + (unsigned)c + 1u;     // REAL end (self incl)
            rp2[node] = rp;
            float r = rsqrtf((float)(c + 1));
            dis[node] = r;
            __half2 h0 = __floats2half2_rn(r * x[node * 3 + 0], r * x[node * 3 + 1]);
            __half2 h1 = __floats2half2_rn(r * x[node * 3 + 2], 0.f);
            uint2 w; w.x = *(unsigned*)&h0; w.y = *(unsigned*)&h1;
            *(uint2*)(sxh + (size_t)node * 4) = w;
        }
    }
    __syncthreads();
    for (int i = tid; i < n; i += 512) {
        unsigned e = ebuf[i];
        int pos = atomicAdd(&fill[(e >> 17) & 127], 1);
        sbuf[pos] = (int)(e & 0x1FFFF);
    }
    __syncthreads();
    // padded per-node writeback: 16 half-waves x 8 nodes; aligned uint4 stores
    // (gp is a multiple of 16 elements: offP entries are round16 prefixes)
    int hw = tid >> 5, hl = tid & 31;
    for (int nd = hw; nd < SPAN; nd += 16) {
        int node = b * SPAN + nd;
        if (node >= N) continue;
        int c = cnt[nd], oc = offC[nd];
        unsigned gp = (unsigned)(base + offP[nd]);
        int pk4 = ((c + 16) & ~15) >> 2;
        for (int j4 = hl; j4 < pk4; j4 += 32) {
            int j = j4 << 2;
            uint4 v;
            v.x = (j     < c) ? (unsigned)sbuf[oc + j]     : ((j     == c) ? (unsigned)node : (unsigned)N);
            v.y = (j + 1 < c) ? (unsigned)sbuf[oc + j + 1] : ((j + 1 == c) ? (unsigned)node : (unsigned)N);
            v.z = (j + 2 < c) ? (unsigned)sbuf[oc + j + 2] : ((j + 2 == c) ? (unsigned)node : (unsigned)N);
            v.w = (j + 3 < c) ? (unsigned)sbuf[oc + j + 3] : ((j + 3 == c) ? (unsigned)node : (unsigned)N);
            *(uint4*)(colb + gp + j) = v;
        }
    }
}

// ---- layer 1: 2 nodes/wave (32 lanes each), 8B gathers; REAL slots only ----
__global__ void agg3_kernel(const __half* __restrict__ sxh, const uint2* __restrict__ rp2,
                            const unsigned* __restrict__ colb, const float* __restrict__ dis,
                            const float* __restrict__ W1, const float* __restrict__ b1,
                            __half* __restrict__ s1h, int N) {
    int wave = (blockIdx.x * blockDim.x + threadIdx.x) >> 6;
    int lane = threadIdx.x & 63;
    int hl = lane & 31;
    int d = wave * 2 + (lane >> 5);
    bool act = d < N;
    int start = 0, end = 0;
    if (act) { uint2 rp = rp2[d]; start = (int)rp.x; end = (int)rp.y; }
    float a0 = 0.f, a1 = 0.f, a2v = 0.f;
    for (int i = start + hl; i < end; i += 32) {   // self included, no pads
        uint2 rq = *(const uint2*)(sxh + (size_t)colb[i] * 4);
        float2 u0 = __half22float2(*(__half2*)&rq.x);
        float2 u1 = __half22float2(*(__half2*)&rq.y);
        a0 += u0.x; a1 += u0.y; a2v += u1.x;
    }
#pragma unroll
    for (int off = 16; off; off >>= 1) {
        a0  += __shfl_xor(a0, off);
        a1  += __shfl_xor(a1, off);
        a2v += __shfl_xor(a2v, off);
    }
    if (act) {
        float r = dis[d];
        float v0 = r * (a0 * W1[hl]      + a1 * W1[64 + hl]      + a2v * W1[128 + hl])      + b1[hl];
        float v1 = r * (a0 * W1[32 + hl] + a1 * W1[96 + hl]      + a2v * W1[160 + hl])      + b1[32 + hl];
        s1h[(size_t)d * 64 + hl]      = __float2half(r * elu(v0));
        s1h[(size_t)d * 64 + 32 + hl] = __float2half(r * elu(v1));
    }
}

// ---- layer 2: 1 node/wave; lane = 8*slot + octet; maskless; plain loads ----
// rp2 holds the real end; padded end re-derived here (pads -> zero row N).
__global__ void agg64_kernel(const __half* __restrict__ s1h, const uint2* __restrict__ rp2,
                             const unsigned* __restrict__ colb, const float* __restrict__ dis,
                             __half* __restrict__ a2h, int N) {
    int wave = (blockIdx.x * blockDim.x + threadIdx.x) >> 6;
    int lane = threadIdx.x & 63;
    int g = lane >> 3;          // edge slot within chunk (0..7)
    int f = lane & 7;           // feature octet: halfs f*8 .. f*8+7 (16B)
    int d = wave;
    if (d >= N) return;
    uint2 rp = rp2[d];
    float r = dis[d];                        // hoisted: overlaps loop latency
    int start = (int)rp.x;
    int len = (int)(rp.y - rp.x);            // real slots (self incl)
    int pend = start + ((len + 15) & ~15);   // padded end
    float acc0 = 0.f, acc1 = 0.f, acc2 = 0.f, acc3 = 0.f;
    float acc4 = 0.f, acc5 = 0.f, acc6 = 0.f, acc7 = 0.f;
    for (int i = start; i < pend; i += 16) {
        int ca = (int)colb[i + g];
        int cb = (int)colb[i + 8 + g];
        uint4 A = *(const uint4*)(s1h + (size_t)ca * 64 + f * 8);
        uint4 B = *(const uint4*)(s1h + (size_t)cb * 64 + f * 8);
        __half2 p0 = __hadd2(*(__half2*)&A.x, *(__half2*)&B.x);
        __half2 p1 = __hadd2(*(__half2*)&A.y, *(__half2*)&B.y);
        __half2 p2 = __hadd2(*(__half2*)&A.z, *(__half2*)&B.z);
        __half2 p3 = __hadd2(*(__half2*)&A.w, *(__half2*)&B.w);
        float2 q0 = __half22float2(p0);
        float2 q1 = __half22float2(p1);
        float2 q2 = __half22float2(p2);
        float2 q3 = __half22float2(p3);
        acc0 += q0.x; acc1 += q0.y; acc2 += q1.x; acc3 += q1.y;
        acc4 += q2.x; acc5 += q2.y; acc6 += q3.x; acc7 += q3.y;
    }
    // reduce across the 8 slot-groups (lane bits 3,4,5)
#pragma unroll
    for (int off = 8; off <= 32; off <<= 1) {
        acc0 += __shfl_xor(acc0, off);
        acc1 += __shfl_xor(acc1, off);
        acc2 += __shfl_xor(acc2, off);
        acc3 += __shfl_xor(acc3, off);
        acc4 += __shfl_xor(acc4, off);
        acc5 += __shfl_xor(acc5, off);
        acc6 += __shfl_xor(acc6, off);
        acc7 += __shfl_xor(acc7, off);
    }
    if (g == 0) {
        __half2 o0 = __floats2half2_rn(r * acc0, r * acc1);
        __half2 o1 = __floats2half2_rn(r * acc2, r * acc3);
        __half2 o2 = __floats2half2_rn(r * acc4, r * acc5);
        __half2 o3 = __floats2half2_rn(r * acc6, r * acc7);
        uint4 w;
        w.x = *(unsigned*)&o0; w.y = *(unsigned*)&o1;
        w.z = *(unsigned*)&o2; w.w = *(unsigned*)&o3;
        *(uint4*)(a2h + (size_t)d * 64 + f * 8) = w;
    }
}

// ---- h1 (all-MFMA): out = softmax(elu(elu(a2h@W2)@Wm1)@Wm2) ----
__global__ __launch_bounds__(256) void h1_kernel(const __half* __restrict__ a2h,
    const __half* __restrict__ W2t, const float* __restrict__ b2g,
    const __half* __restrict__ Wm1t, const float* __restrict__ bm1g,
    const __half* __restrict__ Wm2p, const float* __restrict__ bm2g,
    float* __restrict__ out, int N) {
    __shared__ __align__(16) __half h2s[64 * H2P];   // 11.3 KB
    __shared__ __align__(16) __half ms[64 * MSP2];   // 17.4 KB
    int tid = threadIdx.x;
    int wave = tid >> 6, lane = tid & 63;
    int q = lane >> 4, l16 = lane & 15;
    int base = blockIdx.x * 64;

    v8hf wc[4];
#pragma unroll
    for (int t = 0; t < 4; ++t)
        wc[t] = *(const v8hf*)(Wm2p + ((size_t)(t * 64 + lane)) * 8);
    float bbc = (l16 < 15) ? bm2g[l16] : 0.f;

    // ---- stage A: D[m=node16][n=f] = a2h @ W2 ----
    {
        int nodeRow = base + wave * 16 + l16;
        size_t arow = (size_t)min(nodeRow, N - 1) * 64;
        v8hf af0 = *(const v8hf*)(a2h + arow + q * 8);
        v8hf af1 = *(const v8hf*)(a2h + arow + 32 + q * 8);
#pragma unroll
        for (int fb = 0; fb < 4; ++fb) {
            float bb = b2g[fb * 16 + l16];
            v4f acc = {bb, bb, bb, bb};
            v8hf b0 = *(const v8hf*)(W2t + (fb * 16 + l16) * 64 + q * 8);
            v8hf b1 = *(const v8hf*)(W2t + (fb * 16 + l16) * 64 + 32 + q * 8);
            acc = __builtin_amdgcn_mfma_f32_16x16x32_f16(af0, b0, acc, 0, 0, 0);
            acc = __builtin_amdgcn_mfma_f32_16x16x32_f16(af1, b1, acc, 0, 0, 0);
#pragma unroll
            for (int r = 0; r < 4; ++r)
                h2s[(wave * 16 + q * 4 + r) * H2P + fb * 16 + l16] =
                    __float2half(elu(acc[r]));
        }
    }
    __syncthreads();
    // ---- stage B: D[m=node16][n=j] = h2 @ Wm1 ----
    {
        int arow = (wave * 16 + l16) * H2P;
        v8hf af0 = *(const v8hf*)(h2s + arow + q * 8);
        v8hf af1 = *(const v8hf*)(h2s + arow + 32 + q * 8);
#pragma unroll
        for (int jb = 0; jb < 8; ++jb) {
            float bb = bm1g[jb * 16 + l16];
            v4f acc = {bb, bb, bb, bb};
            v8hf b0 = *(const v8hf*)(Wm1t + (jb * 16 + l16) * 64 + q * 8);
            v8hf b1 = *(const v8hf*)(Wm1t + (jb * 16 + l16) * 64 + 32 + q * 8);
            acc = __builtin_amdgcn_mfma_f32_16x16x32_f16(af0, b0, acc, 0, 0, 0);
            acc = __builtin_amdgcn_mfma_f32_16x16x32_f16(af1, b1, acc, 0, 0, 0);
#pragma unroll
            for (int r = 0; r < 4; ++r)
                ms[(wave * 16 + q * 4 + r) * MSP2 + jb * 16 + l16] =
                    __float2half(elu(acc[r]));
        }
    }
    __syncthreads();
    // ---- stage C: D[m=node16][n=class16] = m @ Wm2 (K=128), shfl softmax ----
    {
        int arow = (wave * 16 + l16) * MSP2;
        v4f accC = {bbc, bbc, bbc, bbc};
#pragma unroll
        for (int t = 0; t < 4; ++t) {
            v8hf a = *(const v8hf*)(ms + arow + t * 32 + q * 8);
            accC = __builtin_amdgcn_mfma_f32_16x16x32_f16(a, wc[t], accC, 0, 0, 0);
        }
#pragma unroll
        for (int r = 0; r < 4; ++r) {
            float lg = (l16 < 15) ? accC[r] : -1e30f;
            float mx = lg;
            mx = fmaxf(mx, __shfl_xor(mx, 1));
            mx = fmaxf(mx, __shfl_xor(mx, 2));
            mx = fmaxf(mx, __shfl_xor(mx, 4));
            mx = fmaxf(mx, __shfl_xor(mx, 8));
            float ex = (l16 < 15) ? __expf(lg - mx) : 0.f;
            float sden = ex;
            sden += __shfl_xor(sden, 1);
            sden += __shfl_xor(sden, 2);
            sden += __shfl_xor(sden, 4);
            sden += __shfl_xor(sden, 8);
            int node = base + wave * 16 + q * 4 + r;
            if (l16 < 15 && node < N)
                out[(size_t)node * 15 + l16] = ex / sden;
        }
    }
}

extern "C" void kernel_launch(void* const* d_in, const int* in_sizes, int n_in,
                              void* d_out, int out_size, void* d_ws, size_t ws_size,
                              hipStream_t stream) {
    const float* x   = (const float*)d_in[0];
    const int*   ei  = (const int*)d_in[1];
    const float* W1  = (const float*)d_in[2];
    const float* b1  = (const float*)d_in[3];
    const float* W2  = (const float*)d_in[4];
    const float* b2  = (const float*)d_in[5];
    const float* Wm1 = (const float*)d_in[6];
    const float* bm1 = (const float*)d_in[7];
    const float* Wm2 = (const float*)d_in[8];
    const float* bm2 = (const float*)d_in[9];
    float* out = (float*)d_out;

    int N = in_sizes[0] / 3;
    int E = in_sizes[1] / 2;
    const int* src = ei;
    const int* dst = ei + E;
    int NBK = (N + SPAN - 1) / SPAN;   // 782

    uintptr_t p = (uintptr_t)d_ws;
    auto carve = [&](size_t bytes) -> void* {
        p = (p + 255) & ~(uintptr_t)255;
        void* r = (void*)p;
        p += bytes;
        return r;
    };
    unsigned* colb    = (unsigned*)carve((size_t)NBK * CAPP * 4 + 256);
    __half*   a2h     = (__half*)carve((size_t)N * 64 * 2);
    __half*   s1h     = (__half*)carve((size_t)(N + 1) * 64 * 2);  // +zero row
    int*      cursor  = (int*)carve((size_t)NBK * 4);
    uint2*    rp2     = (uint2*)carve((size_t)N * 8);
    float*    dis     = (float*)carve((size_t)N * 4);
    __half*   sxh     = (__half*)carve((size_t)(N + 1) * 8);       // +zero row
    __half*   W2t     = (__half*)carve(64 * 64 * 2);
    __half*   Wm1t    = (__half*)carve(128 * 64 * 2);
    __half*   Wm2p    = (__half*)carve(4 * 64 * 8 * 2);

    int nChunks = (E + CH - 1) / CH;          // 391
    int aggBlocks = (N + 7) / 8;              // agg3: 2 nodes/wave, 4 waves/block
    int aggBlocks64 = (N + 3) / 4;            // agg64: 1 node/wave, 4 waves/block
    int nTiles = (N + 63) / 64;               // h1: 64-node tiles

    hipMemsetAsync(cursor, 0, (size_t)NBK * 4, stream);
    scatter_kernel<<<nChunks + 1, 512, 0, stream>>>(src, dst, cursor, colb,
        W2, Wm1, Wm2, W2t, Wm1t, Wm2p, s1h, sxh, E, NBK, nChunks, N);
    csr_sort_kernel<<<NBK, 512, 0, stream>>>(colb, cursor, x, rp2, dis, sxh, N);
    agg3_kernel<<<aggBlocks, 256, 0, stream>>>(sxh, rp2, colb, dis, W1, b1, s1h, N);
    agg64_kernel<<<aggBlocks64, 256, 0, stream>>>(s1h, rp2, colb, dis, a2h, N);
    h1_kernel<<<nTiles, 256, 0, stream>>>(a2h, W2t, b2, Wm1t, bm1, Wm2p, bm2, out, N);
}